// Round 5
// baseline (368.197 us; speedup 1.0000x reference)
//
#include <hip/hip_runtime.h>
#include <hip/hip_bf16.h>

#define HIDDEN 1024
#define HEADS 16
#define HEAD_DIM 64
#define SEQ 2048
#define BATCH 4

typedef __attribute__((ext_vector_type(8))) short bf16x8;
typedef __attribute__((ext_vector_type(4))) float f32x4;
typedef __attribute__((ext_vector_type(16))) float f32x16;
typedef __attribute__((ext_vector_type(4))) short short4v;

static __device__ __forceinline__ unsigned short f2bf(float f) {
  union { float f; unsigned u; } u;
  u.f = f;
  unsigned r = u.u + 0x7fffu + ((u.u >> 16) & 1u);  // RTNE
  return (unsigned short)(r >> 16);
}

static __device__ __forceinline__ unsigned packbf(float lo, float hi) {
  union { __hip_bfloat162 h2; unsigned u; } t;
  t.h2.x = __float2bfloat16(lo);
  t.h2.y = __float2bfloat16(hi);
  return t.u;
}

static __device__ __forceinline__ bf16x8 frag4(unsigned u0, unsigned u1,
                                               unsigned u2, unsigned u3) {
  union { unsigned u[4]; bf16x8 v; } t;
  t.u[0] = u0; t.u[1] = u1; t.u[2] = u2; t.u[3] = u3;
  return t.v;
}

typedef const __attribute__((address_space(1))) unsigned int* gp1_t;
typedef __attribute__((address_space(3))) unsigned int* lp3_t;
static __device__ __forceinline__ void gload_lds16(const void* g, void* l) {
  __builtin_amdgcn_global_load_lds((gp1_t)g, (lp3_t)l, 16, 0, 0);
}

// ---------------- K0: W [K][N] fp32 -> Wt [N][K] bf16 (3 matrices) ----------
__global__ __launch_bounds__(256) void wtrans_kernel(
    const float* __restrict__ Wq, const float* __restrict__ Wk,
    const float* __restrict__ Wv, unsigned short* __restrict__ Wt) {
  __shared__ float tile[64][65];
  int z = blockIdx.z;
  const float* W = (z == 0) ? Wq : (z == 1) ? Wk : Wv;
  int k0 = blockIdx.x * 64, n0 = blockIdx.y * 64;
  int tid = threadIdx.x;
  int tr = tid >> 4;   // 0..15
  int tc = tid & 15;   // 0..15
#pragma unroll
  for (int p = 0; p < 4; ++p) {
    int kk = p * 16 + tr;
    float4 v = *(const float4*)(W + (size_t)(k0 + kk) * HIDDEN + n0 + tc * 4);
    tile[kk][tc * 4 + 0] = v.x; tile[kk][tc * 4 + 1] = v.y;
    tile[kk][tc * 4 + 2] = v.z; tile[kk][tc * 4 + 3] = v.w;
  }
  __syncthreads();
  unsigned short* op = Wt + (size_t)z * HIDDEN * HIDDEN;
#pragma unroll
  for (int p = 0; p < 4; ++p) {
    int nn = p * 16 + tr;
    short4v o;
    o.x = (short)f2bf(tile[tc * 4 + 0][nn]);
    o.y = (short)f2bf(tile[tc * 4 + 1][nn]);
    o.z = (short)f2bf(tile[tc * 4 + 2][nn]);
    o.w = (short)f2bf(tile[tc * 4 + 3][nn]);
    *(short4v*)(op + (size_t)(n0 + nn) * HIDDEN + k0 + tc * 4) = o;
  }
}

// ---------------- K1: LayerNorm: x -> out (xn fp32 residual), xnb (bf16) ----
__global__ __launch_bounds__(256) void ln_kernel(
    const float* __restrict__ x, const float* __restrict__ gamma,
    const float* __restrict__ beta, float* __restrict__ out,
    unsigned short* __restrict__ xnb) {
  int row = blockIdx.x;
  int tid = threadIdx.x;
  const float4* xr = (const float4*)(x + (size_t)row * HIDDEN);
  float4 v = xr[tid];
  float s = v.x + v.y + v.z + v.w;
  float sq = v.x * v.x + v.y * v.y + v.z * v.z + v.w * v.w;
#pragma unroll
  for (int off = 32; off >= 1; off >>= 1) {
    s += __shfl_xor(s, off);
    sq += __shfl_xor(sq, off);
  }
  __shared__ float red[8];
  int wave = tid >> 6, lane = tid & 63;
  if (lane == 0) { red[wave] = s; red[4 + wave] = sq; }
  __syncthreads();
  s = red[0] + red[1] + red[2] + red[3];
  sq = red[4] + red[5] + red[6] + red[7];
  float mu = s * (1.0f / HIDDEN);
  float var = sq * (1.0f / HIDDEN) - mu * mu;
  float rstd = rsqrtf(var + 1e-5f);
  float4 g = ((const float4*)gamma)[tid];
  float4 bt = ((const float4*)beta)[tid];
  float4 o;
  o.x = (v.x - mu) * rstd * g.x + bt.x;
  o.y = (v.y - mu) * rstd * g.y + bt.y;
  o.z = (v.z - mu) * rstd * g.z + bt.z;
  o.w = (v.w - mu) * rstd * g.w + bt.w;
  ((float4*)(out + (size_t)row * HIDDEN))[tid] = o;
  short4v p;
  p.x = (short)f2bf(o.x); p.y = (short)f2bf(o.y);
  p.z = (short)f2bf(o.z); p.w = (short)f2bf(o.w);
  *((short4v*)(xnb + (size_t)row * HIDDEN) + tid) = p;
}

// ---------------- K2: QKV GEMM, m97 structure: 128x128 tile, BK=32 ----------
// q/k bf16 [b,h,s,d] (q pre-scaled by 0.125), v transposed bf16 [b,h,d,s]
__global__ __launch_bounds__(256) void qkv_gemm(
    const unsigned short* __restrict__ xnb, const unsigned short* __restrict__ Wt,
    const float* __restrict__ bq, const float* __restrict__ bk,
    const float* __restrict__ bv, unsigned short* __restrict__ qO,
    unsigned short* __restrict__ kO, unsigned short* __restrict__ vtO) {
  __shared__ unsigned short As[128 * 32];
  __shared__ unsigned short Bs[128 * 32];
  int z = blockIdx.z;
  int m0 = blockIdx.x * 128;
  int n0 = blockIdx.y * 128;
  int tid = threadIdx.x;
  int wave = tid >> 6, lane = tid & 63;
  int lr = lane & 15, g = lane >> 4;
  const unsigned short* Ab = xnb + (size_t)m0 * HIDDEN;
  const unsigned short* Bb = Wt + (size_t)z * HIDDEN * HIDDEN + (size_t)n0 * HIDDEN;
  // staging source coords (lane covers 16B = 8 shorts)
  int srow0 = wave * 32 + (lane >> 2);
  int srow1 = srow0 + 16;
  int scol = (lane & 3) * 8;
  int wm = wave >> 1, wn = wave & 1;
  f32x4 acc[4][4];
#pragma unroll
  for (int i = 0; i < 4; ++i)
#pragma unroll
    for (int j = 0; j < 4; ++j) acc[i][j] = (f32x4){0.f, 0.f, 0.f, 0.f};

#pragma unroll 1
  for (int k0 = 0; k0 < HIDDEN; k0 += 32) {
    gload_lds16(Ab + (size_t)srow0 * HIDDEN + k0 + scol, &As[wave * 1024]);
    gload_lds16(Ab + (size_t)srow1 * HIDDEN + k0 + scol, &As[wave * 1024 + 512]);
    gload_lds16(Bb + (size_t)srow0 * HIDDEN + k0 + scol, &Bs[wave * 1024]);
    gload_lds16(Bb + (size_t)srow1 * HIDDEN + k0 + scol, &Bs[wave * 1024 + 512]);
    __syncthreads();
    bf16x8 aF[4], bF[4];
#pragma unroll
    for (int mb = 0; mb < 4; ++mb)
      aF[mb] = *(const bf16x8*)&As[(wm * 64 + mb * 16 + lr) * 32 + g * 8];
#pragma unroll
    for (int nb = 0; nb < 4; ++nb)
      bF[nb] = *(const bf16x8*)&Bs[(wn * 64 + nb * 16 + lr) * 32 + g * 8];
#pragma unroll
    for (int mb = 0; mb < 4; ++mb)
#pragma unroll
      for (int nb = 0; nb < 4; ++nb)
        acc[mb][nb] = __builtin_amdgcn_mfma_f32_16x16x32_bf16(aF[mb], bF[nb], acc[mb][nb], 0, 0, 0);
    __syncthreads();
  }
  const float* bias = (z == 0) ? bq : (z == 1) ? bk : bv;
  unsigned short* outp = (z == 0) ? qO : (z == 1) ? kO : vtO;
  float scale = (z == 0) ? 0.125f : 1.0f;
#pragma unroll
  for (int nb = 0; nb < 4; ++nb) {
    int n = n0 + wn * 64 + nb * 16 + lr;
    float bsv = bias[n];
    int h = n >> 6, d = n & 63;
#pragma unroll
    for (int mb = 0; mb < 4; ++mb) {
#pragma unroll
      for (int r = 0; r < 4; ++r) {
        int m = m0 + wm * 64 + mb * 16 + g * 4 + r;
        int b = m >> 11, sIdx = m & 2047;
        unsigned short bits = f2bf((acc[mb][nb][r] + bsv) * scale);
        if (z == 2)
          outp[(size_t)((b * HEADS + h) * HEAD_DIM + d) * SEQ + sIdx] = bits;
        else
          outp[(size_t)((b * HEADS + h) * SEQ + sIdx) * HEAD_DIM + d] = bits;
      }
    }
  }
}

// ---------------- K3: flash attention, 32x32 MFMA, fully lane-local --------
// Wave owns 32 q rows (q = lane&31). Swapped QK^T -> scores lane-local;
// PV gives O[d][q] with q on the same lane. No LDS, no barriers.
__global__ __launch_bounds__(256) void attn_kernel(
    const unsigned short* __restrict__ qB, const unsigned short* __restrict__ kB,
    const unsigned short* __restrict__ vtB, float* __restrict__ out) {
  // XCD-aware bijective swizzle: all 16 q-tiles of one head on one XCD.
  int orig = blockIdx.y * gridDim.x + blockIdx.x;  // nwg = 16*64 = 1024
  int swz = (orig & 7) * 128 + (orig >> 3);
  int bx = swz & 15;   // q-tile
  int by = swz >> 4;   // bh
  int b = by >> 4, hh = by & 15;
  int tid = threadIdx.x, wave = tid >> 6, lane = tid & 63;
  int lq = lane & 31;   // q within the wave's 32-row block; also O column
  int hf = lane >> 5;   // half 0/1
  int q0 = bx * 128 + wave * 32;
  const unsigned short* qh = qB + (size_t)by * SEQ * HEAD_DIM;
  const unsigned short* kh = kB + (size_t)by * SEQ * HEAD_DIM;
  const unsigned short* vh = vtB + (size_t)by * HEAD_DIM * SEQ;

  // Q fragments (B-operand of QK): 4 k-steps of 16 along d
  bf16x8 qF[4];
#pragma unroll
  for (int s = 0; s < 4; ++s)
    qF[s] = *(const bf16x8*)(qh + (size_t)(q0 + lq) * HEAD_DIM + s * 16 + hf * 8);

  f32x16 oAcc0, oAcc1;
#pragma unroll
  for (int r = 0; r < 16; ++r) { oAcc0[r] = 0.f; oAcc1[r] = 0.f; }
  float mrun = -1e30f, lrun = 0.f;

#pragma unroll 1
  for (int kv0 = 0; kv0 < SEQ; kv0 += 64) {
    // ---- QK^T: D[k][q]; lane owns q=lq, k = kb*32 + (reg&3)+8*(reg>>2)+4*hf
    f32x16 sc0, sc1;
#pragma unroll
    for (int r = 0; r < 16; ++r) { sc0[r] = 0.f; sc1[r] = 0.f; }
#pragma unroll
    for (int s = 0; s < 4; ++s) {
      bf16x8 kA0 = *(const bf16x8*)(kh + (size_t)(kv0 + lq) * HEAD_DIM + s * 16 + hf * 8);
      bf16x8 kA1 = *(const bf16x8*)(kh + (size_t)(kv0 + 32 + lq) * HEAD_DIM + s * 16 + hf * 8);
      sc0 = __builtin_amdgcn_mfma_f32_32x32x16_bf16(kA0, qF[s], sc0, 0, 0, 0);
      sc1 = __builtin_amdgcn_mfma_f32_32x32x16_bf16(kA1, qF[s], sc1, 0, 0, 0);
    }
    // ---- softmax: lane-local over 32 regs + one half-swap reduce
    float pmax = sc0[0];
#pragma unroll
    for (int r = 1; r < 16; ++r) pmax = fmaxf(pmax, sc0[r]);
#pragma unroll
    for (int r = 0; r < 16; ++r) pmax = fmaxf(pmax, sc1[r]);
    pmax = fmaxf(pmax, __shfl_xor(pmax, 32));
    if (!__all(pmax - mrun <= 8.0f)) {         // defer-max (THR=8)
      float mn = fmaxf(mrun, pmax);
      float alpha = __expf(mrun - mn);
      mrun = mn;
      lrun *= alpha;
#pragma unroll
      for (int r = 0; r < 16; ++r) { oAcc0[r] *= alpha; oAcc1[r] *= alpha; }
    }
    float e0[16], e1[16];
    float lsum = 0.f;
#pragma unroll
    for (int r = 0; r < 16; ++r) {
      e0[r] = __expf(sc0[r] - mrun);
      e1[r] = __expf(sc1[r] - mrun);
      lsum += e0[r] + e1[r];
    }
    lsum += __shfl_xor(lsum, 32);
    lrun += lsum;
    // ---- pack P to bf16 pairs: pk0/pk1[A], A = 4*kb + a; k = 8A + b + 4*hf
    unsigned pk0[8], pk1[8];
#pragma unroll
    for (int a = 0; a < 4; ++a) {
      pk0[a]     = packbf(e0[4 * a + 0], e0[4 * a + 1]);
      pk1[a]     = packbf(e0[4 * a + 2], e0[4 * a + 3]);
      pk0[4 + a] = packbf(e1[4 * a + 0], e1[4 * a + 1]);
      pk1[4 + a] = packbf(e1[4 * a + 2], e1[4 * a + 3]);
    }
    // ---- PV: D[d][q] += V^T-frag x P-frag over 4 k-steps of 16
#pragma unroll
    for (int s = 0; s < 4; ++s) {
      unsigned x0 = pk0[2 * s], y0 = pk0[2 * s + 1];
      unsigned x1 = pk1[2 * s], y1 = pk1[2 * s + 1];
      unsigned sx0 = __shfl_xor(x0, 32), sy0 = __shfl_xor(y0, 32);
      unsigned sx1 = __shfl_xor(x1, 32), sy1 = __shfl_xor(y1, 32);
      // B-frag elems j: j0..3 from half 0 (A=2s+hf), j4..7 from half 1
      unsigned u0 = hf ? sy0 : x0;
      unsigned u1 = hf ? sy1 : x1;
      unsigned u2 = hf ? y0 : sx0;
      unsigned u3 = hf ? y1 : sx1;
      bf16x8 pF = frag4(u0, u1, u2, u3);
      bf16x8 vA0 = *(const bf16x8*)(vh + (size_t)(lq) * SEQ + kv0 + s * 16 + hf * 8);
      bf16x8 vA1 = *(const bf16x8*)(vh + (size_t)(32 + lq) * SEQ + kv0 + s * 16 + hf * 8);
      oAcc0 = __builtin_amdgcn_mfma_f32_32x32x16_bf16(vA0, pF, oAcc0, 0, 0, 0);
      oAcc1 = __builtin_amdgcn_mfma_f32_32x32x16_bf16(vA1, pF, oAcc1, 0, 0, 0);
    }
  }
  // ---- epilogue: out[q][hh*64 + d] += O[d][q] / l;  all state lane-local
  float inv = 1.0f / lrun;
  float* orow = out + ((size_t)b * SEQ + q0 + lq) * HIDDEN + hh * HEAD_DIM;
#pragma unroll
  for (int r = 0; r < 16; ++r) {
    int d0 = (r & 3) + 8 * (r >> 2) + 4 * hf;
    orow[d0] += oAcc0[r] * inv;
    orow[32 + d0] += oAcc1[r] * inv;
  }
}

extern "C" void kernel_launch(void* const* d_in, const int* in_sizes, int n_in,
                              void* d_out, int out_size, void* d_ws, size_t ws_size,
                              hipStream_t stream) {
  const float* x     = (const float*)d_in[0];
  const float* Wq    = (const float*)d_in[1];
  const float* bq    = (const float*)d_in[2];
  const float* Wk    = (const float*)d_in[3];
  const float* bk    = (const float*)d_in[4];
  const float* Wv    = (const float*)d_in[5];
  const float* bv    = (const float*)d_in[6];
  const float* gamma = (const float*)d_in[7];
  const float* beta  = (const float*)d_in[8];
  float* out = (float*)d_out;
  char* ws = (char*)d_ws;
  const size_t MB = 1024 * 1024;
  unsigned short* xnb = (unsigned short*)(ws);              // 16 MB  xn bf16 [8192][1024]
  unsigned short* Wt  = (unsigned short*)(ws + 16 * MB);    //  6 MB  3x Wt[n][k] bf16
  unsigned short* qb  = (unsigned short*)(ws + 22 * MB);    // 16 MB  q [b][h][s][d] (pre-scaled 1/8)
  unsigned short* kb  = (unsigned short*)(ws + 38 * MB);    // 16 MB  k [b][h][s][d]
  unsigned short* vtb = (unsigned short*)(ws + 54 * MB);    // 16 MB  v^T [b][h][d][s]

  hipLaunchKernelGGL(wtrans_kernel, dim3(16, 16, 3), dim3(256), 0, stream, Wq, Wk, Wv, Wt);
  hipLaunchKernelGGL(ln_kernel, dim3(BATCH * SEQ), dim3(256), 0, stream, x, gamma, beta, out, xnb);
  hipLaunchKernelGGL(qkv_gemm, dim3(64, 8, 3), dim3(256), 0, stream, xnb, Wt, bq, bk, bv, qb, kb, vtb);
  hipLaunchKernelGGL(attn_kernel, dim3(16, 64), dim3(256), 0, stream, qb, kb, vtb, out);
}

// Round 6
// 339.321 us; speedup vs baseline: 1.0851x; 1.0851x over previous
//
#include <hip/hip_runtime.h>
#include <hip/hip_bf16.h>

#define HIDDEN 1024
#define HEADS 16
#define HEAD_DIM 64
#define SEQ 2048
#define BATCH 4

typedef __attribute__((ext_vector_type(8))) short bf16x8;
typedef __attribute__((ext_vector_type(4))) float f32x4;
typedef __attribute__((ext_vector_type(16))) float f32x16;
typedef __attribute__((ext_vector_type(4))) short short4v;

static __device__ __forceinline__ unsigned short f2bf(float f) {
  union { float f; unsigned u; } u;
  u.f = f;
  unsigned r = u.u + 0x7fffu + ((u.u >> 16) & 1u);  // RTNE
  return (unsigned short)(r >> 16);
}

static __device__ __forceinline__ unsigned packbf(float lo, float hi) {
  union { __hip_bfloat162 h2; unsigned u; } t;
  t.h2.x = __float2bfloat16(lo);
  t.h2.y = __float2bfloat16(hi);
  return t.u;
}

static __device__ __forceinline__ bf16x8 frag4(unsigned u0, unsigned u1,
                                               unsigned u2, unsigned u3) {
  union { unsigned u[4]; bf16x8 v; } t;
  t.u[0] = u0; t.u[1] = u1; t.u[2] = u2; t.u[3] = u3;
  return t.v;
}

typedef const __attribute__((address_space(1))) unsigned int* gp1_t;
typedef __attribute__((address_space(3))) unsigned int* lp3_t;
static __device__ __forceinline__ void gload_lds16(const void* g, void* l) {
  __builtin_amdgcn_global_load_lds((gp1_t)g, (lp3_t)l, 16, 0, 0);
}

// ---------------- K0: W [K][N] fp32 -> Wt [N][K] bf16 (3 matrices) ----------
__global__ __launch_bounds__(256) void wtrans_kernel(
    const float* __restrict__ Wq, const float* __restrict__ Wk,
    const float* __restrict__ Wv, unsigned short* __restrict__ Wt) {
  __shared__ float tile[64][65];
  int z = blockIdx.z;
  const float* W = (z == 0) ? Wq : (z == 1) ? Wk : Wv;
  int k0 = blockIdx.x * 64, n0 = blockIdx.y * 64;
  int tid = threadIdx.x;
  int tr = tid >> 4;   // 0..15
  int tc = tid & 15;   // 0..15
#pragma unroll
  for (int p = 0; p < 4; ++p) {
    int kk = p * 16 + tr;
    float4 v = *(const float4*)(W + (size_t)(k0 + kk) * HIDDEN + n0 + tc * 4);
    tile[kk][tc * 4 + 0] = v.x; tile[kk][tc * 4 + 1] = v.y;
    tile[kk][tc * 4 + 2] = v.z; tile[kk][tc * 4 + 3] = v.w;
  }
  __syncthreads();
  unsigned short* op = Wt + (size_t)z * HIDDEN * HIDDEN;
#pragma unroll
  for (int p = 0; p < 4; ++p) {
    int nn = p * 16 + tr;
    short4v o;
    o.x = (short)f2bf(tile[tc * 4 + 0][nn]);
    o.y = (short)f2bf(tile[tc * 4 + 1][nn]);
    o.z = (short)f2bf(tile[tc * 4 + 2][nn]);
    o.w = (short)f2bf(tile[tc * 4 + 3][nn]);
    *(short4v*)(op + (size_t)(n0 + nn) * HIDDEN + k0 + tc * 4) = o;
  }
}

// ---------------- K1: LayerNorm: x -> out (xn fp32 residual), xnb (bf16) ----
__global__ __launch_bounds__(256) void ln_kernel(
    const float* __restrict__ x, const float* __restrict__ gamma,
    const float* __restrict__ beta, float* __restrict__ out,
    unsigned short* __restrict__ xnb) {
  int row = blockIdx.x;
  int tid = threadIdx.x;
  const float4* xr = (const float4*)(x + (size_t)row * HIDDEN);
  float4 v = xr[tid];
  float s = v.x + v.y + v.z + v.w;
  float sq = v.x * v.x + v.y * v.y + v.z * v.z + v.w * v.w;
#pragma unroll
  for (int off = 32; off >= 1; off >>= 1) {
    s += __shfl_xor(s, off);
    sq += __shfl_xor(sq, off);
  }
  __shared__ float red[8];
  int wave = tid >> 6, lane = tid & 63;
  if (lane == 0) { red[wave] = s; red[4 + wave] = sq; }
  __syncthreads();
  s = red[0] + red[1] + red[2] + red[3];
  sq = red[4] + red[5] + red[6] + red[7];
  float mu = s * (1.0f / HIDDEN);
  float var = sq * (1.0f / HIDDEN) - mu * mu;
  float rstd = rsqrtf(var + 1e-5f);
  float4 g = ((const float4*)gamma)[tid];
  float4 bt = ((const float4*)beta)[tid];
  float4 o;
  o.x = (v.x - mu) * rstd * g.x + bt.x;
  o.y = (v.y - mu) * rstd * g.y + bt.y;
  o.z = (v.z - mu) * rstd * g.z + bt.z;
  o.w = (v.w - mu) * rstd * g.w + bt.w;
  ((float4*)(out + (size_t)row * HIDDEN))[tid] = o;
  short4v p;
  p.x = (short)f2bf(o.x); p.y = (short)f2bf(o.y);
  p.z = (short)f2bf(o.z); p.w = (short)f2bf(o.w);
  *((short4v*)(xnb + (size_t)row * HIDDEN) + tid) = p;
}

// ---------------- K2: QKV GEMM, m97 structure: 128x128 tile, BK=32 ----------
// q/k bf16 [b,h,s,d] (q pre-scaled by 0.125), v transposed bf16 [b,h,d,s]
__global__ __launch_bounds__(256) void qkv_gemm(
    const unsigned short* __restrict__ xnb, const unsigned short* __restrict__ Wt,
    const float* __restrict__ bq, const float* __restrict__ bk,
    const float* __restrict__ bv, unsigned short* __restrict__ qO,
    unsigned short* __restrict__ kO, unsigned short* __restrict__ vtO) {
  __shared__ unsigned short As[128 * 32];
  __shared__ unsigned short Bs[128 * 32];
  int z = blockIdx.z;
  int m0 = blockIdx.x * 128;
  int n0 = blockIdx.y * 128;
  int tid = threadIdx.x;
  int wave = tid >> 6, lane = tid & 63;
  int lr = lane & 15, g = lane >> 4;
  const unsigned short* Ab = xnb + (size_t)m0 * HIDDEN;
  const unsigned short* Bb = Wt + (size_t)z * HIDDEN * HIDDEN + (size_t)n0 * HIDDEN;
  // staging source coords (lane covers 16B = 8 shorts)
  int srow0 = wave * 32 + (lane >> 2);
  int srow1 = srow0 + 16;
  int scol = (lane & 3) * 8;
  int wm = wave >> 1, wn = wave & 1;
  f32x4 acc[4][4];
#pragma unroll
  for (int i = 0; i < 4; ++i)
#pragma unroll
    for (int j = 0; j < 4; ++j) acc[i][j] = (f32x4){0.f, 0.f, 0.f, 0.f};

#pragma unroll 1
  for (int k0 = 0; k0 < HIDDEN; k0 += 32) {
    gload_lds16(Ab + (size_t)srow0 * HIDDEN + k0 + scol, &As[wave * 1024]);
    gload_lds16(Ab + (size_t)srow1 * HIDDEN + k0 + scol, &As[wave * 1024 + 512]);
    gload_lds16(Bb + (size_t)srow0 * HIDDEN + k0 + scol, &Bs[wave * 1024]);
    gload_lds16(Bb + (size_t)srow1 * HIDDEN + k0 + scol, &Bs[wave * 1024 + 512]);
    __syncthreads();
    bf16x8 aF[4], bF[4];
#pragma unroll
    for (int mb = 0; mb < 4; ++mb)
      aF[mb] = *(const bf16x8*)&As[(wm * 64 + mb * 16 + lr) * 32 + g * 8];
#pragma unroll
    for (int nb = 0; nb < 4; ++nb)
      bF[nb] = *(const bf16x8*)&Bs[(wn * 64 + nb * 16 + lr) * 32 + g * 8];
#pragma unroll
    for (int mb = 0; mb < 4; ++mb)
#pragma unroll
      for (int nb = 0; nb < 4; ++nb)
        acc[mb][nb] = __builtin_amdgcn_mfma_f32_16x16x32_bf16(aF[mb], bF[nb], acc[mb][nb], 0, 0, 0);
    __syncthreads();
  }
  const float* bias = (z == 0) ? bq : (z == 1) ? bk : bv;
  unsigned short* outp = (z == 0) ? qO : (z == 1) ? kO : vtO;
  float scale = (z == 0) ? 0.125f : 1.0f;
#pragma unroll
  for (int nb = 0; nb < 4; ++nb) {
    int n = n0 + wn * 64 + nb * 16 + lr;
    float bsv = bias[n];
    int h = n >> 6, d = n & 63;
#pragma unroll
    for (int mb = 0; mb < 4; ++mb) {
#pragma unroll
      for (int r = 0; r < 4; ++r) {
        int m = m0 + wm * 64 + mb * 16 + g * 4 + r;
        int b = m >> 11, sIdx = m & 2047;
        unsigned short bits = f2bf((acc[mb][nb][r] + bsv) * scale);
        if (z == 2)
          outp[(size_t)((b * HEADS + h) * HEAD_DIM + d) * SEQ + sIdx] = bits;
        else
          outp[(size_t)((b * HEADS + h) * SEQ + sIdx) * HEAD_DIM + d] = bits;
      }
    }
  }
}

// ---------------- K3: flash attention, 32x32 MFMA, dual-stream -------------
// One full KV tile (64 rows) for one stream; branchless online softmax.
static __device__ __forceinline__ void do_tile(
    const unsigned short* __restrict__ kh, const unsigned short* __restrict__ vh,
    int kv0, int lq, int hf, const bf16x8 (&qF)[4],
    float& mrun, float& lrun, f32x16& o0, f32x16& o1) {
  // K and V loads issued together up front (V covers under QK+softmax)
  bf16x8 kA0[4], kA1[4], vA0[4], vA1[4];
#pragma unroll
  for (int s = 0; s < 4; ++s) {
    kA0[s] = *(const bf16x8*)(kh + (size_t)(kv0 + lq) * HEAD_DIM + s * 16 + hf * 8);
    kA1[s] = *(const bf16x8*)(kh + (size_t)(kv0 + 32 + lq) * HEAD_DIM + s * 16 + hf * 8);
    vA0[s] = *(const bf16x8*)(vh + (size_t)lq * SEQ + kv0 + s * 16 + hf * 8);
    vA1[s] = *(const bf16x8*)(vh + (size_t)(32 + lq) * SEQ + kv0 + s * 16 + hf * 8);
  }
  // QK^T swapped: D[k][q]; lane owns q=lq, 32 scores (16 per row-block)
  f32x16 sc0, sc1;
#pragma unroll
  for (int r = 0; r < 16; ++r) { sc0[r] = 0.f; sc1[r] = 0.f; }
#pragma unroll
  for (int s = 0; s < 4; ++s) {
    sc0 = __builtin_amdgcn_mfma_f32_32x32x16_bf16(kA0[s], qF[s], sc0, 0, 0, 0);
    sc1 = __builtin_amdgcn_mfma_f32_32x32x16_bf16(kA1[s], qF[s], sc1, 0, 0, 0);
  }
  // balanced max tree + one cross-half reduce
  float m0[8];
#pragma unroll
  for (int r = 0; r < 8; ++r)
    m0[r] = fmaxf(fmaxf(sc0[r], sc0[r + 8]), fmaxf(sc1[r], sc1[r + 8]));
#pragma unroll
  for (int r = 0; r < 4; ++r) m0[r] = fmaxf(m0[r], m0[r + 4]);
  float pmax = fmaxf(fmaxf(m0[0], m0[1]), fmaxf(m0[2], m0[3]));
  pmax = fmaxf(pmax, __shfl_xor(pmax, 32));
  // branchless online rescale (alpha == 1.0 when max didn't grow)
  float mn = fmaxf(mrun, pmax);
  float alpha = __expf(mrun - mn);
  mrun = mn;
  lrun *= alpha;
#pragma unroll
  for (int r = 0; r < 16; ++r) { o0[r] *= alpha; o1[r] *= alpha; }
  float e0[16], e1[16];
  float ls0 = 0.f, ls1 = 0.f;
#pragma unroll
  for (int r = 0; r < 16; ++r) {
    e0[r] = __expf(sc0[r] - mn);
    e1[r] = __expf(sc1[r] - mn);
    ls0 += e0[r]; ls1 += e1[r];
  }
  float lsum = ls0 + ls1;
  lsum += __shfl_xor(lsum, 32);
  lrun += lsum;
  // pack P: pk0/pk1[A], A = 4*kb + a; k = 8A + b + 4*hf
  unsigned pk0[8], pk1[8];
#pragma unroll
  for (int a = 0; a < 4; ++a) {
    pk0[a]     = packbf(e0[4 * a + 0], e0[4 * a + 1]);
    pk1[a]     = packbf(e0[4 * a + 2], e0[4 * a + 3]);
    pk0[4 + a] = packbf(e1[4 * a + 0], e1[4 * a + 1]);
    pk1[4 + a] = packbf(e1[4 * a + 2], e1[4 * a + 3]);
  }
  // single-shfl-per-pair cross-half exchange (operand pre-selected per half)
  unsigned t0[4], t1[4];
#pragma unroll
  for (int s = 0; s < 4; ++s) {
    t0[s] = __shfl_xor(hf ? pk0[2 * s] : pk0[2 * s + 1], 32);
    t1[s] = __shfl_xor(hf ? pk1[2 * s] : pk1[2 * s + 1], 32);
  }
  // PV: D[d][q] += V^T-frag x P-frag over 4 k-steps of 16
#pragma unroll
  for (int s = 0; s < 4; ++s) {
    unsigned u0 = hf ? t0[s] : pk0[2 * s];
    unsigned u1 = hf ? t1[s] : pk1[2 * s];
    unsigned u2 = hf ? pk0[2 * s + 1] : t0[s];
    unsigned u3 = hf ? pk1[2 * s + 1] : t1[s];
    bf16x8 pF = frag4(u0, u1, u2, u3);
    o0 = __builtin_amdgcn_mfma_f32_32x32x16_bf16(vA0[s], pF, o0, 0, 0, 0);
    o1 = __builtin_amdgcn_mfma_f32_32x32x16_bf16(vA1[s], pF, o1, 0, 0, 0);
  }
}

__global__ __launch_bounds__(256, 2) void attn_kernel(
    const unsigned short* __restrict__ qB, const unsigned short* __restrict__ kB,
    const unsigned short* __restrict__ vtB, float* __restrict__ out) {
  // XCD-aware bijective swizzle: all 16 q-tiles of one head on one XCD.
  int orig = blockIdx.y * gridDim.x + blockIdx.x;  // nwg = 16*64 = 1024
  int swz = (orig & 7) * 128 + (orig >> 3);
  int bx = swz & 15;   // q-tile
  int by = swz >> 4;   // bh
  int b = by >> 4, hh = by & 15;
  int tid = threadIdx.x, wave = tid >> 6, lane = tid & 63;
  int lq = lane & 31;   // q within the wave's 32-row block; also O column
  int hf = lane >> 5;   // half 0/1
  int q0 = bx * 128 + wave * 32;
  const unsigned short* qh = qB + (size_t)by * SEQ * HEAD_DIM;
  const unsigned short* kh = kB + (size_t)by * SEQ * HEAD_DIM;
  const unsigned short* vh = vtB + (size_t)by * HEAD_DIM * SEQ;

  bf16x8 qF[4];
#pragma unroll
  for (int s = 0; s < 4; ++s)
    qF[s] = *(const bf16x8*)(qh + (size_t)(q0 + lq) * HEAD_DIM + s * 16 + hf * 8);

  f32x16 o0A, o1A, o0B, o1B;
#pragma unroll
  for (int r = 0; r < 16; ++r) { o0A[r] = 0.f; o1A[r] = 0.f; o0B[r] = 0.f; o1B[r] = 0.f; }
  float mA = -1e30f, lA = 0.f, mB = -1e30f, lB = 0.f;

#pragma unroll 1
  for (int jj = 0; jj < 16; ++jj) {
    do_tile(kh, vh, jj * 64, lq, hf, qF, mA, lA, o0A, o1A);
    do_tile(kh, vh, 1024 + jj * 64, lq, hf, qF, mB, lB, o0B, o1B);
  }
  // merge the two streams (all lane-local) and write out
  float m = fmaxf(mA, mB);
  float aA = __expf(mA - m), aB = __expf(mB - m);
  float l = lA * aA + lB * aB;
  float inv = 1.0f / l;
  float cA = aA * inv, cB = aB * inv;
  float* orow = out + ((size_t)b * SEQ + q0 + lq) * HIDDEN + hh * HEAD_DIM;
#pragma unroll
  for (int r = 0; r < 16; ++r) {
    int d0 = (r & 3) + 8 * (r >> 2) + 4 * hf;
    orow[d0]      += o0A[r] * cA + o0B[r] * cB;
    orow[32 + d0] += o1A[r] * cA + o1B[r] * cB;
  }
}

extern "C" void kernel_launch(void* const* d_in, const int* in_sizes, int n_in,
                              void* d_out, int out_size, void* d_ws, size_t ws_size,
                              hipStream_t stream) {
  const float* x     = (const float*)d_in[0];
  const float* Wq    = (const float*)d_in[1];
  const float* bq    = (const float*)d_in[2];
  const float* Wk    = (const float*)d_in[3];
  const float* bk    = (const float*)d_in[4];
  const float* Wv    = (const float*)d_in[5];
  const float* bv    = (const float*)d_in[6];
  const float* gamma = (const float*)d_in[7];
  const float* beta  = (const float*)d_in[8];
  float* out = (float*)d_out;
  char* ws = (char*)d_ws;
  const size_t MB = 1024 * 1024;
  unsigned short* xnb = (unsigned short*)(ws);              // 16 MB  xn bf16 [8192][1024]
  unsigned short* Wt  = (unsigned short*)(ws + 16 * MB);    //  6 MB  3x Wt[n][k] bf16
  unsigned short* qb  = (unsigned short*)(ws + 22 * MB);    // 16 MB  q [b][h][s][d] (pre-scaled 1/8)
  unsigned short* kb  = (unsigned short*)(ws + 38 * MB);    // 16 MB  k [b][h][s][d]
  unsigned short* vtb = (unsigned short*)(ws + 54 * MB);    // 16 MB  v^T [b][h][d][s]

  hipLaunchKernelGGL(wtrans_kernel, dim3(16, 16, 3), dim3(256), 0, stream, Wq, Wk, Wv, Wt);
  hipLaunchKernelGGL(ln_kernel, dim3(BATCH * SEQ), dim3(256), 0, stream, x, gamma, beta, out, xnb);
  hipLaunchKernelGGL(qkv_gemm, dim3(64, 8, 3), dim3(256), 0, stream, xnb, Wt, bq, bk, bv, qb, kb, vtb);
  hipLaunchKernelGGL(attn_kernel, dim3(16, 64), dim3(256), 0, stream, qb, kb, vtb, out);
}

// Round 7
// 213.254 us; speedup vs baseline: 1.7266x; 1.5912x over previous
//
#include <hip/hip_runtime.h>
#include <hip/hip_bf16.h>

#define HIDDEN 1024
#define HEADS 16
#define HEAD_DIM 64
#define SEQ 2048
#define BATCH 4

typedef __attribute__((ext_vector_type(8))) short bf16x8;
typedef __attribute__((ext_vector_type(4))) float f32x4;
typedef __attribute__((ext_vector_type(16))) float f32x16;
typedef __attribute__((ext_vector_type(4))) short short4v;

static __device__ __forceinline__ unsigned short f2bf(float f) {
  union { float f; unsigned u; } u;
  u.f = f;
  unsigned r = u.u + 0x7fffu + ((u.u >> 16) & 1u);  // RTNE
  return (unsigned short)(r >> 16);
}

static __device__ __forceinline__ unsigned packbf(float lo, float hi) {
  union { __hip_bfloat162 h2; unsigned u; } t;
  t.h2.x = __float2bfloat16(lo);
  t.h2.y = __float2bfloat16(hi);
  return t.u;
}

static __device__ __forceinline__ bf16x8 frag4(unsigned u0, unsigned u1,
                                               unsigned u2, unsigned u3) {
  union { unsigned u[4]; bf16x8 v; } t;
  t.u[0] = u0; t.u[1] = u1; t.u[2] = u2; t.u[3] = u3;
  return t.v;
}

typedef const __attribute__((address_space(1))) unsigned int* gp1_t;
typedef __attribute__((address_space(3))) unsigned int* lp3_t;
static __device__ __forceinline__ void gload_lds16(const void* g, void* l) {
  __builtin_amdgcn_global_load_lds((gp1_t)g, (lp3_t)l, 16, 0, 0);
}

// ---------------- K0: W [K][N] fp32 -> Wt [N][K] bf16 (3 matrices) ----------
__global__ __launch_bounds__(256) void wtrans_kernel(
    const float* __restrict__ Wq, const float* __restrict__ Wk,
    const float* __restrict__ Wv, unsigned short* __restrict__ Wt) {
  __shared__ float tile[64][65];
  int z = blockIdx.z;
  const float* W = (z == 0) ? Wq : (z == 1) ? Wk : Wv;
  int k0 = blockIdx.x * 64, n0 = blockIdx.y * 64;
  int tid = threadIdx.x;
  int tr = tid >> 4;   // 0..15
  int tc = tid & 15;   // 0..15
#pragma unroll
  for (int p = 0; p < 4; ++p) {
    int kk = p * 16 + tr;
    float4 v = *(const float4*)(W + (size_t)(k0 + kk) * HIDDEN + n0 + tc * 4);
    tile[kk][tc * 4 + 0] = v.x; tile[kk][tc * 4 + 1] = v.y;
    tile[kk][tc * 4 + 2] = v.z; tile[kk][tc * 4 + 3] = v.w;
  }
  __syncthreads();
  unsigned short* op = Wt + (size_t)z * HIDDEN * HIDDEN;
#pragma unroll
  for (int p = 0; p < 4; ++p) {
    int nn = p * 16 + tr;
    short4v o;
    o.x = (short)f2bf(tile[tc * 4 + 0][nn]);
    o.y = (short)f2bf(tile[tc * 4 + 1][nn]);
    o.z = (short)f2bf(tile[tc * 4 + 2][nn]);
    o.w = (short)f2bf(tile[tc * 4 + 3][nn]);
    *(short4v*)(op + (size_t)(n0 + nn) * HIDDEN + k0 + tc * 4) = o;
  }
}

// ---------------- K1: LayerNorm: x -> out (xn fp32 residual), xnb (bf16) ----
__global__ __launch_bounds__(256) void ln_kernel(
    const float* __restrict__ x, const float* __restrict__ gamma,
    const float* __restrict__ beta, float* __restrict__ out,
    unsigned short* __restrict__ xnb) {
  int row = blockIdx.x;
  int tid = threadIdx.x;
  const float4* xr = (const float4*)(x + (size_t)row * HIDDEN);
  float4 v = xr[tid];
  float s = v.x + v.y + v.z + v.w;
  float sq = v.x * v.x + v.y * v.y + v.z * v.z + v.w * v.w;
#pragma unroll
  for (int off = 32; off >= 1; off >>= 1) {
    s += __shfl_xor(s, off);
    sq += __shfl_xor(sq, off);
  }
  __shared__ float red[8];
  int wave = tid >> 6, lane = tid & 63;
  if (lane == 0) { red[wave] = s; red[4 + wave] = sq; }
  __syncthreads();
  s = red[0] + red[1] + red[2] + red[3];
  sq = red[4] + red[5] + red[6] + red[7];
  float mu = s * (1.0f / HIDDEN);
  float var = sq * (1.0f / HIDDEN) - mu * mu;
  float rstd = rsqrtf(var + 1e-5f);
  float4 g = ((const float4*)gamma)[tid];
  float4 bt = ((const float4*)beta)[tid];
  float4 o;
  o.x = (v.x - mu) * rstd * g.x + bt.x;
  o.y = (v.y - mu) * rstd * g.y + bt.y;
  o.z = (v.z - mu) * rstd * g.z + bt.z;
  o.w = (v.w - mu) * rstd * g.w + bt.w;
  ((float4*)(out + (size_t)row * HIDDEN))[tid] = o;
  short4v p;
  p.x = (short)f2bf(o.x); p.y = (short)f2bf(o.y);
  p.z = (short)f2bf(o.z); p.w = (short)f2bf(o.w);
  *((short4v*)(xnb + (size_t)row * HIDDEN) + tid) = p;
}

// ---------------- K2: QKV GEMM, m97 structure: 128x128 tile, BK=32 ----------
// q/k bf16 [b,h,s,d] (q pre-scaled by 0.125), v transposed bf16 [b,h,d,s]
__global__ __launch_bounds__(256) void qkv_gemm(
    const unsigned short* __restrict__ xnb, const unsigned short* __restrict__ Wt,
    const float* __restrict__ bq, const float* __restrict__ bk,
    const float* __restrict__ bv, unsigned short* __restrict__ qO,
    unsigned short* __restrict__ kO, unsigned short* __restrict__ vtO) {
  __shared__ unsigned short As[128 * 32];
  __shared__ unsigned short Bs[128 * 32];
  int z = blockIdx.z;
  int m0 = blockIdx.x * 128;
  int n0 = blockIdx.y * 128;
  int tid = threadIdx.x;
  int wave = tid >> 6, lane = tid & 63;
  int lr = lane & 15, g = lane >> 4;
  const unsigned short* Ab = xnb + (size_t)m0 * HIDDEN;
  const unsigned short* Bb = Wt + (size_t)z * HIDDEN * HIDDEN + (size_t)n0 * HIDDEN;
  // staging source coords (lane covers 16B = 8 shorts)
  int srow0 = wave * 32 + (lane >> 2);
  int srow1 = srow0 + 16;
  int scol = (lane & 3) * 8;
  int wm = wave >> 1, wn = wave & 1;
  f32x4 acc[4][4];
#pragma unroll
  for (int i = 0; i < 4; ++i)
#pragma unroll
    for (int j = 0; j < 4; ++j) acc[i][j] = (f32x4){0.f, 0.f, 0.f, 0.f};

#pragma unroll 1
  for (int k0 = 0; k0 < HIDDEN; k0 += 32) {
    gload_lds16(Ab + (size_t)srow0 * HIDDEN + k0 + scol, &As[wave * 1024]);
    gload_lds16(Ab + (size_t)srow1 * HIDDEN + k0 + scol, &As[wave * 1024 + 512]);
    gload_lds16(Bb + (size_t)srow0 * HIDDEN + k0 + scol, &Bs[wave * 1024]);
    gload_lds16(Bb + (size_t)srow1 * HIDDEN + k0 + scol, &Bs[wave * 1024 + 512]);
    __syncthreads();
    bf16x8 aF[4], bF[4];
#pragma unroll
    for (int mb = 0; mb < 4; ++mb)
      aF[mb] = *(const bf16x8*)&As[(wm * 64 + mb * 16 + lr) * 32 + g * 8];
#pragma unroll
    for (int nb = 0; nb < 4; ++nb)
      bF[nb] = *(const bf16x8*)&Bs[(wn * 64 + nb * 16 + lr) * 32 + g * 8];
#pragma unroll
    for (int mb = 0; mb < 4; ++mb)
#pragma unroll
      for (int nb = 0; nb < 4; ++nb)
        acc[mb][nb] = __builtin_amdgcn_mfma_f32_16x16x32_bf16(aF[mb], bF[nb], acc[mb][nb], 0, 0, 0);
    __syncthreads();
  }
  const float* bias = (z == 0) ? bq : (z == 1) ? bk : bv;
  unsigned short* outp = (z == 0) ? qO : (z == 1) ? kO : vtO;
  float scale = (z == 0) ? 0.125f : 1.0f;
#pragma unroll
  for (int nb = 0; nb < 4; ++nb) {
    int n = n0 + wn * 64 + nb * 16 + lr;
    float bsv = bias[n];
    int h = n >> 6, d = n & 63;
#pragma unroll
    for (int mb = 0; mb < 4; ++mb) {
#pragma unroll
      for (int r = 0; r < 4; ++r) {
        int m = m0 + wm * 64 + mb * 16 + g * 4 + r;
        int b = m >> 11, sIdx = m & 2047;
        unsigned short bits = f2bf((acc[mb][nb][r] + bsv) * scale);
        if (z == 2)
          outp[(size_t)((b * HEADS + h) * HEAD_DIM + d) * SEQ + sIdx] = bits;
        else
          outp[(size_t)((b * HEADS + h) * SEQ + sIdx) * HEAD_DIM + d] = bits;
      }
    }
  }
}

// ---------------- K3: flash attention, LDS-staged K/V, swizzled, pipelined -
// Block: 128 q rows (4 waves x 32). K/V tiles (64 kv rows) staged to LDS by
// all 4 waves via global_load_lds (linear dest, pre-swizzled source), read
// back with the same XOR involution: byte ^= ((row&7)<<4). 1-deep prefetch.
__global__ __launch_bounds__(256, 2) void attn_kernel(
    const unsigned short* __restrict__ qB, const unsigned short* __restrict__ kB,
    const unsigned short* __restrict__ vtB, float* __restrict__ out) {
  __shared__ unsigned short Kt[2][64 * 64];
  __shared__ unsigned short Vt[2][64 * 64];
  // XCD-aware bijective swizzle: 8 heads' full KV sets per XCD (4MB = L2).
  int orig = blockIdx.y * gridDim.x + blockIdx.x;  // nwg = 16*64 = 1024
  int swz = (orig & 7) * 128 + (orig >> 3);
  int bx = swz & 15;   // q-tile
  int by = swz >> 4;   // bh
  int b = by >> 4, hh = by & 15;
  int tid = threadIdx.x, wave = tid >> 6, lane = tid & 63;
  int lq = lane & 31;   // q row within wave block; also O column
  int hf = lane >> 5;   // half 0/1
  int q0 = bx * 128 + wave * 32;
  const unsigned short* qh = qB + (size_t)by * SEQ * HEAD_DIM;
  const unsigned short* kh = kB + (size_t)by * SEQ * HEAD_DIM;
  const unsigned short* vh = vtB + (size_t)by * HEAD_DIM * SEQ;

  bf16x8 qF[4];
#pragma unroll
  for (int s = 0; s < 4; ++s)
    qF[s] = *(const bf16x8*)(qh + (size_t)(q0 + lq) * HEAD_DIM + s * 16 + hf * 8);

  // staging coords: lane covers LDS bytes slotbase + lane*16 (linear dest);
  // logical row = slot*8 + (lane>>3), in-row 16B index = (lane&7)^(lane>>3)
  int srow = wave * 16 + (lane >> 3);          // rows for slot i=0 (i adds 8)
  int scoff = ((lane & 7) ^ (lane >> 3)) << 3; // shorts within row
  // read offsets (shorts into 64x64 tile), same involution
  int xorb = (lq & 7) << 4;
  int koff[4];
#pragma unroll
  for (int s = 0; s < 4; ++s)
    koff[s] = (lq * 128 + ((s * 32 + hf * 16) ^ xorb)) >> 1;

  f32x16 o0, o1;
#pragma unroll
  for (int r = 0; r < 16; ++r) { o0[r] = 0.f; o1[r] = 0.f; }
  float mrun = -1e30f, lrun = 0.f;

  // prologue: stage tile 0 into buf 0
#pragma unroll
  for (int i = 0; i < 2; ++i) {
    int row = srow + i * 8;
    gload_lds16(kh + (size_t)row * HEAD_DIM + scoff, &Kt[0][(wave * 2 + i) * 512]);
    gload_lds16(vh + (size_t)row * SEQ + scoff, &Vt[0][(wave * 2 + i) * 512]);
  }
  __syncthreads();

#pragma unroll 1
  for (int t = 0; t < 32; ++t) {
    int cur = t & 1;
    // stage next tile into the other buffer (in flight during compute)
    if (t < 31) {
      int kv1 = (t + 1) * 64;
#pragma unroll
      for (int i = 0; i < 2; ++i) {
        int row = srow + i * 8;
        gload_lds16(kh + (size_t)(kv1 + row) * HEAD_DIM + scoff,
                    &Kt[cur ^ 1][(wave * 2 + i) * 512]);
        gload_lds16(vh + (size_t)row * SEQ + kv1 + scoff,
                    &Vt[cur ^ 1][(wave * 2 + i) * 512]);
      }
    }
    const unsigned short* Kb = Kt[cur];
    const unsigned short* Vb = Vt[cur];
    // ---- QK^T swapped: D[k][q]; lane owns q=lq, 32 scores
    f32x16 sc0, sc1;
#pragma unroll
    for (int r = 0; r < 16; ++r) { sc0[r] = 0.f; sc1[r] = 0.f; }
    __builtin_amdgcn_s_setprio(1);
#pragma unroll
    for (int s = 0; s < 4; ++s) {
      bf16x8 k0 = *(const bf16x8*)&Kb[koff[s]];
      bf16x8 k1 = *(const bf16x8*)&Kb[koff[s] + 2048];
      sc0 = __builtin_amdgcn_mfma_f32_32x32x16_bf16(k0, qF[s], sc0, 0, 0, 0);
      sc1 = __builtin_amdgcn_mfma_f32_32x32x16_bf16(k1, qF[s], sc1, 0, 0, 0);
    }
    __builtin_amdgcn_s_setprio(0);
    // ---- max + defer-max rescale
    float m8[8];
#pragma unroll
    for (int r = 0; r < 8; ++r)
      m8[r] = fmaxf(fmaxf(sc0[r], sc0[r + 8]), fmaxf(sc1[r], sc1[r + 8]));
#pragma unroll
    for (int r = 0; r < 4; ++r) m8[r] = fmaxf(m8[r], m8[r + 4]);
    float pmax = fmaxf(fmaxf(m8[0], m8[1]), fmaxf(m8[2], m8[3]));
    pmax = fmaxf(pmax, __shfl_xor(pmax, 32));
    if (!__all(pmax - mrun <= 8.0f)) {
      float mn = fmaxf(mrun, pmax);
      float alpha = __expf(mrun - mn);
      mrun = mn;
      lrun *= alpha;
#pragma unroll
      for (int r = 0; r < 16; ++r) { o0[r] *= alpha; o1[r] *= alpha; }
    }
    // ---- fused softmax + PV per 16-k block
    float lsum = 0.f;
    __builtin_amdgcn_s_setprio(1);
#pragma unroll
    for (int s = 0; s < 4; ++s) {
      float e[8];
#pragma unroll
      for (int j = 0; j < 8; ++j) {
        float scv = (s < 2) ? sc0[8 * s + j] : sc1[8 * (s - 2) + j];
        e[j] = __expf(scv - mrun);
        lsum += e[j];
      }
      unsigned pa0 = packbf(e[0], e[1]);
      unsigned pb0 = packbf(e[2], e[3]);
      unsigned pa1 = packbf(e[4], e[5]);
      unsigned pb1 = packbf(e[6], e[7]);
      unsigned t0 = __shfl_xor(hf ? pa0 : pa1, 32);
      unsigned t1 = __shfl_xor(hf ? pb0 : pb1, 32);
      unsigned u0 = hf ? t0 : pa0;
      unsigned u1 = hf ? t1 : pb0;
      unsigned u2 = hf ? pa1 : t0;
      unsigned u3 = hf ? pb1 : t1;
      bf16x8 pF = frag4(u0, u1, u2, u3);
      bf16x8 v0 = *(const bf16x8*)&Vb[koff[s]];
      bf16x8 v1 = *(const bf16x8*)&Vb[koff[s] + 2048];
      o0 = __builtin_amdgcn_mfma_f32_32x32x16_bf16(v0, pF, o0, 0, 0, 0);
      o1 = __builtin_amdgcn_mfma_f32_32x32x16_bf16(v1, pF, o1, 0, 0, 0);
    }
    __builtin_amdgcn_s_setprio(0);
    lsum += __shfl_xor(lsum, 32);
    lrun += lsum;
    __syncthreads();  // compiler drains vmcnt before barrier: next tile ready
  }
  // ---- epilogue: out[q][hh*64 + d] += O[d][q] / l;  all state lane-local
  float inv = 1.0f / lrun;
  float* orow = out + ((size_t)b * SEQ + q0 + lq) * HIDDEN + hh * HEAD_DIM;
#pragma unroll
  for (int r = 0; r < 16; ++r) {
    int d0 = (r & 3) + 8 * (r >> 2) + 4 * hf;
    orow[d0] += o0[r] * inv;
    orow[32 + d0] += o1[r] * inv;
  }
}

extern "C" void kernel_launch(void* const* d_in, const int* in_sizes, int n_in,
                              void* d_out, int out_size, void* d_ws, size_t ws_size,
                              hipStream_t stream) {
  const float* x     = (const float*)d_in[0];
  const float* Wq    = (const float*)d_in[1];
  const float* bq    = (const float*)d_in[2];
  const float* Wk    = (const float*)d_in[3];
  const float* bk    = (const float*)d_in[4];
  const float* Wv    = (const float*)d_in[5];
  const float* bv    = (const float*)d_in[6];
  const float* gamma = (const float*)d_in[7];
  const float* beta  = (const float*)d_in[8];
  float* out = (float*)d_out;
  char* ws = (char*)d_ws;
  const size_t MB = 1024 * 1024;
  unsigned short* xnb = (unsigned short*)(ws);              // 16 MB  xn bf16 [8192][1024]
  unsigned short* Wt  = (unsigned short*)(ws + 16 * MB);    //  6 MB  3x Wt[n][k] bf16
  unsigned short* qb  = (unsigned short*)(ws + 22 * MB);    // 16 MB  q [b][h][s][d] (pre-scaled 1/8)
  unsigned short* kb  = (unsigned short*)(ws + 38 * MB);    // 16 MB  k [b][h][s][d]
  unsigned short* vtb = (unsigned short*)(ws + 54 * MB);    // 16 MB  v^T [b][h][d][s]

  hipLaunchKernelGGL(wtrans_kernel, dim3(16, 16, 3), dim3(256), 0, stream, Wq, Wk, Wv, Wt);
  hipLaunchKernelGGL(ln_kernel, dim3(BATCH * SEQ), dim3(256), 0, stream, x, gamma, beta, out, xnb);
  hipLaunchKernelGGL(qkv_gemm, dim3(64, 8, 3), dim3(256), 0, stream, xnb, Wt, bq, bk, bv, qb, kb, vtb);
  hipLaunchKernelGGL(attn_kernel, dim3(16, 64), dim3(256), 0, stream, qb, kb, vtb, out);
}